// Round 1
// baseline (377.882 us; speedup 1.0000x reference)
//
#include <hip/hip_runtime.h>
#include <hip/hip_bf16.h>

typedef __attribute__((ext_vector_type(8)))  short bf16x8;
typedef __attribute__((ext_vector_type(16))) float f32x16;
typedef __attribute__((ext_vector_type(4)))  float f32x4;

#define NN 50000
#define EE 800000
#define HH 128
#define KK 320   /* 2H + B */
#define NEG 0.01f

__device__ __forceinline__ unsigned pack2(float a, float b) {
    unsigned short lo = __builtin_bit_cast(unsigned short, __float2bfloat16(a));
    unsigned short hi = __builtin_bit_cast(unsigned short, __float2bfloat16(b));
    return (unsigned)lo | ((unsigned)hi << 16);
}

__global__ __launch_bounds__(256, 2) void fused_edge_kernel(
    const float* __restrict__ feat, const float* __restrict__ gdf,
    const float* __restrict__ W,    const float* __restrict__ bias,
    const int*   __restrict__ src,  const int*   __restrict__ dst,
    float* __restrict__ out)
{
    __shared__ int4 lds4[64 * 40];   // 64 rows x 640B (320 bf16) per row
    __shared__ int  dsts[64];
    char* lds = (char*)lds4;

    const int tid  = threadIdx.x;
    const int lane = tid & 63;
    const int wid  = tid >> 6;               // wave 0..3, owns cols [wid*32, wid*32+32)
    const long long ebase = (long long)blockIdx.x * 64;

    // ---- W fragments for this wave's 32 columns (f32 -> bf16, kept in VGPRs) ----
    const int col   = wid * 32 + (lane & 31);
    const int khalf = lane >> 5;             // 0/1: which 8-wide k-half of each k16 step
    bf16x8 Wb[20];
    {
        const float* wrow = W + col * KK + khalf * 8;
        #pragma unroll
        for (int k = 0; k < 20; k++) {
            f32x4 x0 = *(const f32x4*)(wrow + k * 16);
            f32x4 x1 = *(const f32x4*)(wrow + k * 16 + 4);
            union { bf16x8 v; unsigned u[4]; } t;
            t.u[0] = pack2(x0[0], x0[1]); t.u[1] = pack2(x0[2], x0[3]);
            t.u[2] = pack2(x1[0], x1[1]); t.u[3] = pack2(x1[2], x1[3]);
            Wb[k] = t.v;
        }
    }

    // ---- stage A tile: 64 edges x [feat[src](128) | feat[dst](128) | gdf(64)] as bf16 ----
    {
        const int r = tid >> 2, q = tid & 3;     // 4 threads per edge row
        const long long e = ebase + r;
        const int s = src[e], d = dst[e];
        if (q == 0) dsts[r] = d;
        const float* fs = feat + (long long)s * HH;
        const float* fd = feat + (long long)d * HH;
        const float* ge = gdf  + (long long)e * 64;
        #pragma unroll
        for (int i = 0; i < 10; i++) {
            const int c = q + i * 4;             // 16B-output chunk 0..39 (8 bf16 each)
            const float* p = (c < 16) ? (fs + c * 8)
                           : (c < 32) ? (fd + (c - 16) * 8)
                                      : (ge + (c - 32) * 8);
            f32x4 v0 = *(const f32x4*)p;
            f32x4 v1 = *(const f32x4*)(p + 4);
            int4 h;
            h.x = (int)pack2(v0[0], v0[1]); h.y = (int)pack2(v0[2], v0[3]);
            h.z = (int)pack2(v1[0], v1[1]); h.w = (int)pack2(v1[2], v1[3]);
            // XOR swizzle keeps 16B units; banks balanced for writes and b128 reads
            *(int4*)(lds + r * 640 + ((c * 16) ^ ((r & 7) << 4))) = h;
        }
    }
    __syncthreads();

    // ---- MFMA main loop: D[64 x 32cols] += A[64 x 320] * W^T slice ----
    f32x16 acc0 = {}; f32x16 acc1 = {};
    const int arow = lane & 31;
    const int xr   = (arow & 7) << 4;
    #pragma unroll
    for (int k = 0; k < 20; k++) {
        const int kb = k * 32 + khalf * 16;
        bf16x8 a0 = *(const bf16x8*)(lds + arow * 640 + (kb ^ xr));
        bf16x8 a1 = *(const bf16x8*)(lds + (arow + 32) * 640 + (kb ^ xr));
        acc0 = __builtin_amdgcn_mfma_f32_32x32x16_bf16(a0, Wb[k], acc0, 0, 0, 0);
        acc1 = __builtin_amdgcn_mfma_f32_32x32x16_bf16(a1, Wb[k], acc1, 0, 0, 0);
    }

    // ---- epilogue: bias + sigmoid*leakyrelu, scatter-add to out[dst] ----
    const float bv = bias[col];
    #pragma unroll
    for (int rt = 0; rt < 2; rt++) {
        const f32x16 A = rt ? acc1 : acc0;
        #pragma unroll
        for (int g = 0; g < 4; g++) {
            #pragma unroll
            for (int j = 0; j < 4; j++) {
                const int reg = g * 4 + j;
                const int row = j + g * 8 + khalf * 4;   // C/D: row=(reg&3)+8*(reg>>2)+4*(lane>>5)
                const float z  = A[reg] + bv;
                const float lr = z > 0.f ? z : NEG * z;
                const float sg = __builtin_amdgcn_rcpf(1.f + __expf(-z));
                const int dn = dsts[rt * 32 + row];
                unsafeAtomicAdd(out + (long long)dn * HH + col, lr * sg);
            }
        }
    }
}

extern "C" void kernel_launch(void* const* d_in, const int* in_sizes, int n_in,
                              void* d_out, int out_size, void* d_ws, size_t ws_size,
                              hipStream_t stream) {
    const float* feat = (const float*)d_in[0];
    const float* gdf  = (const float*)d_in[1];
    const float* W    = (const float*)d_in[2];
    const float* bias = (const float*)d_in[3];
    const int*   src  = (const int*)d_in[4];
    const int*   dst  = (const int*)d_in[5];
    float* out = (float*)d_out;

    hipMemsetAsync(out, 0, (size_t)out_size * sizeof(float), stream);
    fused_edge_kernel<<<EE / 64, 256, 0, stream>>>(feat, gdf, W, bias, src, dst, out);
}

// Round 3
// 326.018 us; speedup vs baseline: 1.1591x; 1.1591x over previous
//
#include <hip/hip_runtime.h>
#include <hip/hip_bf16.h>

typedef __attribute__((ext_vector_type(8)))  short bf16x8;
typedef __attribute__((ext_vector_type(16))) float f32x16;
typedef __attribute__((ext_vector_type(4)))  float f32x4;
typedef __attribute__((ext_vector_type(2)))  __fp16 fp16x2;

#define NN 50000
#define EE 800000
#define HH 128
#define KK 320   /* 2H + B */
#define NEG 0.01f
#define NTILES (EE / 64)
#define NBLK 768   /* 256 CU x 3 resident blocks */

__device__ __forceinline__ unsigned pack2(float a, float b) {
    unsigned short lo = __builtin_bit_cast(unsigned short, __float2bfloat16(a));
    unsigned short hi = __builtin_bit_cast(unsigned short, __float2bfloat16(b));
    return (unsigned)lo | ((unsigned)hi << 16);
}

template<int USE_F16>
__global__ __launch_bounds__(256, 3) void fused_edge_kernel(
    const float* __restrict__ feat, const float* __restrict__ gdf,
    const float* __restrict__ W,    const float* __restrict__ bias,
    const int*   __restrict__ src,  const int*   __restrict__ dst,
    float* __restrict__ out, __fp16* __restrict__ acc16)
{
    __shared__ int4 lds4[64 * 40];   // 64 rows x 640B (320 bf16)
    __shared__ int  dsts[64];
    char* lds = (char*)lds4;

    const int tid  = threadIdx.x;
    const int lane = tid & 63;
    const int wid  = tid >> 6;               // wave owns cols [wid*32, wid*32+32)
    const int col  = wid * 32 + (lane & 31);
    const int khalf = lane >> 5;             // which 8-wide k-half of each k16 step
    const int r = tid >> 2, q = tid & 3;     // 4 threads per edge row (staging)

    // ---- W fragments for this wave's 32 columns (f32 -> bf16, in VGPRs, once) ----
    bf16x8 Wb[20];
    {
        const float* wrow = W + col * KK + khalf * 8;
        #pragma unroll
        for (int k = 0; k < 20; k++) {
            f32x4 x0 = *(const f32x4*)(wrow + k * 16);
            f32x4 x1 = *(const f32x4*)(wrow + k * 16 + 4);
            union { bf16x8 v; unsigned u[4]; } t;
            t.u[0] = pack2(x0[0], x0[1]); t.u[1] = pack2(x0[2], x0[3]);
            t.u[2] = pack2(x1[0], x1[1]); t.u[3] = pack2(x1[2], x1[3]);
            Wb[k] = t.v;
        }
    }
    const float bv = bias[col];

    int tile = blockIdx.x;
    int sCur = src[(long long)tile * 64 + r];
    int dCur = dst[(long long)tile * 64 + r];

    while (tile < NTILES) {
        const long long ebase = (long long)tile * 64;

        // ---- stage A tile: [feat[src](128) | feat[dst](128) | gdf(64)] as bf16 ----
        if (q == 0) dsts[r] = dCur;
        {
            const float* fs = feat + (long long)sCur * HH;
            const float* fd = feat + (long long)dCur * HH;
            const float* ge = gdf  + (ebase + r) * 64;
            #pragma unroll
            for (int i = 0; i < 10; i++) {
                const int c = q + i * 4;             // compile-time per unrolled iter
                const float* p = (c < 16) ? (fs + c * 8)
                               : (c < 32) ? (fd + (c - 16) * 8)
                                          : (ge + (c - 32) * 8);
                f32x4 v0 = *(const f32x4*)p;
                f32x4 v1 = *(const f32x4*)(p + 4);
                int4 h;
                h.x = (int)pack2(v0[0], v0[1]); h.y = (int)pack2(v0[2], v0[3]);
                h.z = (int)pack2(v1[0], v1[1]); h.w = (int)pack2(v1[2], v1[3]);
                *(int4*)(lds + r * 640 + ((c * 16) ^ ((r & 7) << 4))) = h;
            }
        }
        __syncthreads();

        // ---- prefetch next tile's indices (breaks idx->gather dep chain) ----
        const int nt = tile + NBLK;
        if (nt < NTILES) {
            sCur = src[(long long)nt * 64 + r];
            dCur = dst[(long long)nt * 64 + r];
        }

        // ---- MFMA: D[64 x 32cols] += A[64 x 320] * W^T slice ----
        f32x16 acc0 = {}; f32x16 acc1 = {};
        const int arow = lane & 31;
        const int xr   = (arow & 7) << 4;
        #pragma unroll
        for (int k = 0; k < 20; k++) {
            const int kb = k * 32 + khalf * 16;
            bf16x8 a0 = *(const bf16x8*)(lds + arow * 640 + (kb ^ xr));
            bf16x8 a1 = *(const bf16x8*)(lds + (arow + 32) * 640 + (kb ^ xr));
            acc0 = __builtin_amdgcn_mfma_f32_32x32x16_bf16(a0, Wb[k], acc0, 0, 0, 0);
            acc1 = __builtin_amdgcn_mfma_f32_32x32x16_bf16(a1, Wb[k], acc1, 0, 0, 0);
        }

        // ---- epilogue: bias + sigmoid*leakyrelu, scatter-add ----
        #pragma unroll
        for (int rt = 0; rt < 2; rt++) {
            const f32x16 A = rt ? acc1 : acc0;
            #pragma unroll
            for (int g = 0; g < 4; g++) {
                #pragma unroll
                for (int j = 0; j < 4; j++) {
                    const int reg = g * 4 + j;
                    const int row = j + g * 8 + khalf * 4;   // C/D row mapping
                    const float z  = A[reg] + bv;
                    const float lr = z > 0.f ? z : NEG * z;
                    const float sg = 1.f / (1.f + __expf(-z));
                    const float m  = lr * sg;
                    const int dn = dsts[rt * 32 + row];
                    if (USE_F16) {
                        const float o = __shfl_xor(m, 1);   // neighbor col's value
                        if (!(lane & 1)) {                  // even lane: cols (col, col+1)
                            fp16x2 hv = __builtin_amdgcn_cvt_pkrtz(m, o);
                            __fp16* p = acc16 + (long long)dn * HH + col;
                            asm volatile("global_atomic_pk_add_f16 %0, %1, off"
                                         :: "v"(p), "v"(hv) : "memory");
                        }
                    } else {
                        unsafeAtomicAdd(out + (long long)dn * HH + col, m);
                    }
                }
            }
        }
        __syncthreads();   // protect lds/dsts before next tile's staging
        tile = nt;
    }
}

__global__ __launch_bounds__(256) void conv_kernel(const int4* __restrict__ acc,
                                                   float4* __restrict__ out)
{
    const int i = blockIdx.x * 256 + threadIdx.x;   // 800000 threads x 8 halves
    union { int4 v; __fp16 h[8]; } u;
    u.v = acc[i];
    float4 a, b;
    a.x = (float)u.h[0]; a.y = (float)u.h[1]; a.z = (float)u.h[2]; a.w = (float)u.h[3];
    b.x = (float)u.h[4]; b.y = (float)u.h[5]; b.z = (float)u.h[6]; b.w = (float)u.h[7];
    out[2 * i]     = a;
    out[2 * i + 1] = b;
}

extern "C" void kernel_launch(void* const* d_in, const int* in_sizes, int n_in,
                              void* d_out, int out_size, void* d_ws, size_t ws_size,
                              hipStream_t stream) {
    const float* feat = (const float*)d_in[0];
    const float* gdf  = (const float*)d_in[1];
    const float* W    = (const float*)d_in[2];
    const float* bias = (const float*)d_in[3];
    const int*   src  = (const int*)d_in[4];
    const int*   dst  = (const int*)d_in[5];
    float* out = (float*)d_out;

    const size_t accBytes = (size_t)NN * HH * sizeof(__fp16);   // 12.8 MB
    if (ws_size >= accBytes) {
        (void)hipMemsetAsync(d_ws, 0, accBytes, stream);
        fused_edge_kernel<1><<<NBLK, 256, 0, stream>>>(feat, gdf, W, bias, src, dst,
                                                       out, (__fp16*)d_ws);
        conv_kernel<<<(NN * HH / 8) / 256, 256, 0, stream>>>((const int4*)d_ws,
                                                             (float4*)out);
    } else {
        (void)hipMemsetAsync(out, 0, (size_t)out_size * sizeof(float), stream);
        fused_edge_kernel<0><<<NBLK, 256, 0, stream>>>(feat, gdf, W, bias, src, dst,
                                                       out, (__fp16*)d_ws);
    }
}